// Round 2
// baseline (481.309 us; speedup 1.0000x reference)
//
#include <hip/hip_runtime.h>
#include <cmath>

// Problem constants (from reference setup_inputs)
constexpr int Bdim = 64;
constexpr int Fdim = 4096;
constexpr int Edim = 256;
constexpr int Hdim = 512;
constexpr int Udim = 512;

typedef __attribute__((ext_vector_type(8))) short short8;   // 8 bf16 (16B)
typedef __attribute__((ext_vector_type(4))) float f32x4;

// ---------------------------------------------------------------------------
// Helpers
// ---------------------------------------------------------------------------
__device__ __forceinline__ unsigned short f2bf(float f) {
    unsigned int u = __float_as_uint(f);
    u += 0x7FFFu + ((u >> 16) & 1u);   // RNE; inputs finite
    return (unsigned short)(u >> 16);
}
__device__ __forceinline__ unsigned int pack2(float lo, float hi) {
    return (unsigned int)f2bf(lo) | ((unsigned int)f2bf(hi) << 16);
}
__device__ __forceinline__ float tanh_fast(float x) {
    float e = __expf(2.0f * x);
    return 1.0f - 2.0f * __builtin_amdgcn_rcpf(e + 1.0f);
}
// async global->LDS, 16B per lane; lds dest is wave-uniform base + lane*16
__device__ __forceinline__ void gload_lds16(const void* g, void* l) {
    __builtin_amdgcn_global_load_lds(
        (const __attribute__((address_space(1))) unsigned int*)g,
        (__attribute__((address_space(3))) unsigned int*)l, 16, 0, 0);
}

// ---------------------------------------------------------------------------
// Kernel 1 (fused prep): blocks 0..127   : cb[b][u] = W1b[u]+W2b[u]+hidden.W2
//                        blocks 128..159 : W1 -> transposed/swizzled bf16 W1Ts
//                        blocks 160..175 : zero ctx (replaces hipMemsetAsync)
// ---------------------------------------------------------------------------
__global__ __launch_bounds__(256) void prep_kernel(
    const float* __restrict__ hidden, const float* __restrict__ W2,
    const float* __restrict__ W1b, const float* __restrict__ W2b,
    float* __restrict__ cb,
    const float* __restrict__ W1, unsigned short* __restrict__ Th,
    float* __restrict__ ctx, const int do_t)
{
    const int bid = blockIdx.x;
    const int tid = threadIdx.x;

    if (bid < 128) {
        // ---- proj_h ----
        const int b = bid >> 1;
        const int u = (bid & 1) * 256 + tid;
        const float* hb = hidden + (size_t)b * Hdim;
        float acc = 0.f;
        #pragma unroll 8
        for (int h = 0; h < Hdim; ++h)
            acc = fmaf(hb[h], W2[(size_t)h * Udim + u], acc);
        cb[(size_t)b * Udim + u] = acc + W1b[u] + W2b[u];
    } else if (bid < 160) {
        // ---- w1t: W1 (E,U) fp32 -> bf16 [U][E] with 16B-chunk XOR swizzle
        if (!do_t) return;
        __shared__ unsigned short sT[64][72];
        const int k  = bid - 128;            // 0..31 : (4 e-tiles) x (8 u-tiles)
        const int e0 = (k & 3) * 64, u0 = (k >> 2) * 64;
        const int ue = tid & 63, er = tid >> 6;
        #pragma unroll
        for (int it = 0; it < 16; ++it) {
            const int e = er + it * 4;
            sT[ue][e] = f2bf(W1[(size_t)(e0 + e) * Udim + u0 + ue]);
        }
        __syncthreads();
        const int ur = tid >> 2, cq = tid & 3;
        const int u = u0 + ur, s = u & 7;
        const int cA = (e0 >> 3) + cq * 2;   // global 16B-chunk index
        uint4 a  = *(const uint4*)&sT[ur][cq * 16];
        uint4 b2 = *(const uint4*)&sT[ur][cq * 16 + 8];
        unsigned short* dst = Th + (size_t)u * Edim;
        *(uint4*)(dst + ((cA ^ s) << 3))       = a;
        *(uint4*)(dst + (((cA + 1) ^ s) << 3)) = b2;
    } else {
        // ---- zero ctx ----
        const int idx = (bid - 160) * 256 + tid;
        ((float4*)ctx)[idx] = make_float4(0.f, 0.f, 0.f, 0.f);
    }
}

// ---------------------------------------------------------------------------
// Kernel 2 (dominant): scores via bf16 MFMA.
// 64 f-rows per block (grid 64x64), 4 waves x 16 rows -> af[8] = 32 VGPR.
// Forced 4 blocks/CU (LDS 33,792 B, <=128 VGPR): 16 blocks/CU over the kernel
// stagger phase-A HBM bursts against pass-loop compute -> HBM stays fed.
// B: 16 u-passes of 32 rows (16 KB) double-buffered, prefetch issued before
// compute, drained by the end-of-pass barrier (covered by MFMA+tanh).
// Writes RAW scores (+Vb) to workspace; normalization happens downstream.
// ---------------------------------------------------------------------------
__global__ __launch_bounds__(256, 4) void score_mfma4_kernel(
    const float* __restrict__ feat,            // [B][F][E] fp32
    const unsigned short* __restrict__ W1Ts,   // [U][E] bf16, chunk-swizzled
    const float* __restrict__ Vw, const float* __restrict__ Vb,
    const float* __restrict__ cb, float* __restrict__ scr)
{
    __shared__ unsigned short lds[16896];   // 33,792 B: A-scratch / B dbuf

    const int b    = blockIdx.y;
    const int f0   = blockIdx.x * 64;
    const int tid  = threadIdx.x;
    const int lane = tid & 63;
    const int w    = tid >> 6;          // wave id; 16 f-rows each
    const int ln15 = lane & 15;
    const int kq   = lane >> 4;         // 0..3
    const int swz  = ln15 & 7;

    // ---- Phase A: stage+convert 16 f-rows into af[8] (32 VGPRs) ----
    short8 af[8];
    {
        unsigned short* sAw = lds + w * 4224;   // 16 rows x 264 shorts per wave
        const float* gA = feat + ((size_t)(b * Fdim + f0 + w * 16)) * Edim;
        #pragma unroll
        for (int r = 0; r < 16; ++r) {
            float4 v = *(const float4*)(gA + (size_t)r * Edim + lane * 4);
            uint2 p; p.x = pack2(v.x, v.y); p.y = pack2(v.z, v.w);
            *(uint2*)&sAw[r * 264 + lane * 4] = p;
        }
        #pragma unroll
        for (int k8 = 0; k8 < 8; ++k8)
            af[k8] = *(const short8*)&sAw[ln15 * 264 + k8 * 32 + kq * 8];
    }
    __syncthreads();   // all waves done with A scratch before B overwrites it

    float sacc[4] = {};
    const float* cbB = cb + (size_t)b * Udim;

    // ---- prologue: stage pass 0 (u-rows 0..31, 16 KB) into buf0 ----
    {
        const char* gB = (const char*)W1Ts;
        #pragma unroll
        for (int t = 0; t < 4; ++t) {
            const int chunk = w * 4 + t;   // 16 x 1 KB
            gload_lds16(gB + (size_t)chunk * 1024 + lane * 16,
                        (char*)lds + chunk * 1024);
        }
    }
    __syncthreads();

    for (int p = 0; p < 16; ++p) {
        // issue-early prefetch of next window into the other buffer
        if (p < 15) {
            const char* gB = (const char*)(W1Ts + (size_t)(p + 1) * 32 * Edim);
            char* lb = (char*)lds + ((p + 1) & 1) * 16384;
            #pragma unroll
            for (int t = 0; t < 4; ++t) {
                const int chunk = w * 4 + t;
                gload_lds16(gB + (size_t)chunk * 1024 + lane * 16,
                            lb + chunk * 1024);
            }
        }

        const unsigned short* bw = lds + (p & 1) * 8192;   // current window
        const int ub = p * 32;
        const float cu0 = cbB[ub + ln15],     cu1 = cbB[ub + 16 + ln15];
        const float vv0 = Vw[ub + ln15],      vv1 = Vw[ub + 16 + ln15];
        f32x4 acc0 = {}, acc1 = {};
        #pragma unroll
        for (int k8 = 0; k8 < 8; ++k8) {
            const int co = ((k8 * 4 + kq) ^ swz) * 8;   // swizzled chunk
            short8 b0 = *(const short8*)&bw[ln15 * 256 + co];
            short8 b1 = *(const short8*)&bw[(16 + ln15) * 256 + co];
            acc0 = __builtin_amdgcn_mfma_f32_16x16x32_bf16(af[k8], b0, acc0, 0, 0, 0);
            acc1 = __builtin_amdgcn_mfma_f32_16x16x32_bf16(af[k8], b1, acc1, 0, 0, 0);
        }
        // fused epilogue: tanh + V-dot into running per-f partials
        #pragma unroll
        for (int r = 0; r < 4; ++r)
            sacc[r] += tanh_fast(acc0[r] + cu0) * vv0
                     + tanh_fast(acc1[r] + cu1) * vv1;

        if (p < 15) __syncthreads();   // reads done before buf reuse; drains
    }                                  // prefetch (covered by compute above)

    // ---- reduce over u-lanes (ln15), store raw scores (+Vb) ----
    const float vb = Vb[0];
    #pragma unroll
    for (int r = 0; r < 4; ++r) {
        float s = sacc[r];
        s += __shfl_xor(s, 1);
        s += __shfl_xor(s, 2);
        s += __shfl_xor(s, 4);
        s += __shfl_xor(s, 8);
        if (ln15 == 0)
            scr[(size_t)b * Fdim + f0 + w * 16 + kq * 4 + r] = s + vb;
    }
}

// ---------------------------------------------------------------------------
// Kernel 3 (fused): per-block redundant softmax stats (L2-resident row read,
// identical reduction order in every block -> bit-identical weights),
// normalized weights written once, context accumulated via float4 loads +
// LDS reduce + one atomicAdd set per block.
// ---------------------------------------------------------------------------
__global__ __launch_bounds__(256) void ctxnorm_kernel(
    const float* __restrict__ feat, const float* __restrict__ scr,
    float* __restrict__ wts, float* __restrict__ ctx)
{
    __shared__ float  red[8];
    __shared__ float  wl[256];
    __shared__ float4 sred[256];

    const int b   = blockIdx.y;
    const int fc  = blockIdx.x;        // 0..15
    const int f0  = fc * 256;
    const int tid = threadIdx.x;
    const float* row = scr + (size_t)b * Fdim;

    // ---- stats over the full raw row ----
    float v[16];
    float m = -INFINITY;
    #pragma unroll
    for (int i = 0; i < 16; ++i) {
        v[i] = row[tid + 256 * i];
        m = fmaxf(m, v[i]);
    }
    #pragma unroll
    for (int off = 1; off < 64; off <<= 1)
        m = fmaxf(m, __shfl_xor(m, off));
    if ((tid & 63) == 0) red[tid >> 6] = m;
    __syncthreads();
    m = fmaxf(fmaxf(red[0], red[1]), fmaxf(red[2], red[3]));

    float s = 0.f;
    #pragma unroll
    for (int i = 0; i < 16; ++i)
        s += expf(v[i] - m);
    #pragma unroll
    for (int off = 1; off < 64; off <<= 1)
        s += __shfl_xor(s, off);
    if ((tid & 63) == 0) red[4 + (tid >> 6)] = s;   // disjoint slots, no hazard
    __syncthreads();
    const float inv = 1.0f / (red[4] + red[5] + red[6] + red[7]);

    // ---- own chunk's normalized weight (v[fc] == row[f0 + tid]) ----
    const float wgt = expf(v[fc] - m) * inv;
    wts[(size_t)b * Fdim + f0 + tid] = wgt;
    wl[tid] = wgt;
    __syncthreads();

    // ---- context accumulation ----
    const int e4 = tid & 63;   // float4 column
    const int fg = tid >> 6;   // f-row group (0..3)
    const float4* fp = (const float4*)(feat + ((size_t)b * Fdim + f0) * Edim);

    float4 a = make_float4(0.f, 0.f, 0.f, 0.f);
    #pragma unroll 8
    for (int i = 0; i < 64; ++i) {
        const int f = i * 4 + fg;
        const float4 fv = fp[(size_t)f * 64 + e4];
        const float wv = wl[f];
        a.x = fmaf(wv, fv.x, a.x);
        a.y = fmaf(wv, fv.y, a.y);
        a.z = fmaf(wv, fv.z, a.z);
        a.w = fmaf(wv, fv.w, a.w);
    }
    sred[tid] = a;
    __syncthreads();

    if (fg == 0) {
        const float4 r0 = sred[e4];
        const float4 r1 = sred[64 + e4];
        const float4 r2 = sred[128 + e4];
        const float4 r3 = sred[192 + e4];
        float* cp = ctx + (size_t)b * Edim + e4 * 4;
        atomicAdd(cp + 0, r0.x + r1.x + r2.x + r3.x);
        atomicAdd(cp + 1, r0.y + r1.y + r2.y + r3.y);
        atomicAdd(cp + 2, r0.z + r1.z + r2.z + r3.z);
        atomicAdd(cp + 3, r0.w + r1.w + r2.w + r3.w);
    }
}

// ---------------------------------------------------------------------------
// Fallback path (ws too small): fp32 score -> in-place softmax -> context
// ---------------------------------------------------------------------------
constexpr int TFt = 64;
constexpr int TUt = 64;
constexpr int LDR = Edim + 4;

__global__ __launch_bounds__(256) void score_kernel(
    const float* __restrict__ feat, const float* __restrict__ W1,
    const float* __restrict__ Vw, const float* __restrict__ Vb,
    const float* __restrict__ cb, float* __restrict__ scores)
{
    __shared__ float sA[TFt * LDR];
    __shared__ float sW[TUt * LDR];

    const int b   = blockIdx.y;
    const int f0  = blockIdx.x * TFt;
    const int tid = threadIdx.x;
    const int tf  = tid >> 4;
    const int tu  = tid & 15;

    {
        const float4* gA = (const float4*)(feat + ((size_t)b * Fdim + f0) * Edim);
        #pragma unroll
        for (int it = 0; it < 16; ++it) {
            const int i = tid + it * 256;
            const int f = i >> 6;
            const int qq = i & 63;
            const float4 v = gA[i];
            *(float4*)&sA[f * LDR + 4 * qq] = v;
        }
    }

    float sacc[4] = {0.f, 0.f, 0.f, 0.f};
    const float* cbb = cb + (size_t)b * Udim;

    for (int uc = 0; uc < Udim; uc += TUt) {
        __syncthreads();
        #pragma unroll
        for (int it = 0; it < 16; ++it) {
            const int i = tid + it * 256;
            const int e = i >> 4;
            const int qq = i & 15;
            const float4 v = *(const float4*)(W1 + (size_t)e * Udim + uc + 4 * qq);
            sW[(4 * qq + 0) * LDR + e] = v.x;
            sW[(4 * qq + 1) * LDR + e] = v.y;
            sW[(4 * qq + 2) * LDR + e] = v.z;
            sW[(4 * qq + 3) * LDR + e] = v.w;
        }
        __syncthreads();

        float acc[4][4] = {};
        #pragma unroll 4
        for (int e = 0; e < Edim; e += 4) {
            float4 a0 = *(const float4*)&sA[(tf +  0) * LDR + e];
            float4 a1 = *(const float4*)&sA[(tf + 16) * LDR + e];
            float4 a2 = *(const float4*)&sA[(tf + 32) * LDR + e];
            float4 a3 = *(const float4*)&sA[(tf + 48) * LDR + e];
            float4 w0 = *(const float4*)&sW[(tu +  0) * LDR + e];
            float4 w1 = *(const float4*)&sW[(tu + 16) * LDR + e];
            float4 w2 = *(const float4*)&sW[(tu + 32) * LDR + e];
            float4 w3 = *(const float4*)&sW[(tu + 48) * LDR + e];
            #define FMA4(i, j, A, W)                         \
                acc[i][j] = fmaf(A.x, W.x, acc[i][j]);       \
                acc[i][j] = fmaf(A.y, W.y, acc[i][j]);       \
                acc[i][j] = fmaf(A.z, W.z, acc[i][j]);       \
                acc[i][j] = fmaf(A.w, W.w, acc[i][j]);
            FMA4(0,0,a0,w0) FMA4(0,1,a0,w1) FMA4(0,2,a0,w2) FMA4(0,3,a0,w3)
            FMA4(1,0,a1,w0) FMA4(1,1,a1,w1) FMA4(1,2,a1,w2) FMA4(1,3,a1,w3)
            FMA4(2,0,a2,w0) FMA4(2,1,a2,w1) FMA4(2,2,a2,w2) FMA4(2,3,a2,w3)
            FMA4(3,0,a3,w0) FMA4(3,1,a3,w1) FMA4(3,2,a3,w2) FMA4(3,3,a3,w3)
            #undef FMA4
        }

        #pragma unroll
        for (int j = 0; j < 4; ++j) {
            const int u = uc + tu + 16 * j;
            const float vw = Vw[u];
            const float cuv = cbb[u];
            #pragma unroll
            for (int i = 0; i < 4; ++i)
                sacc[i] = fmaf(tanhf(acc[i][j] + cuv), vw, sacc[i]);
        }
    }

    const float vb = Vb[0];
    #pragma unroll
    for (int i = 0; i < 4; ++i) {
        float s = sacc[i];
        s += __shfl_xor(s, 1);
        s += __shfl_xor(s, 2);
        s += __shfl_xor(s, 4);
        s += __shfl_xor(s, 8);
        if (tu == 0)
            scores[(size_t)b * Fdim + f0 + tf + 16 * i] = s + vb;
    }
}

__global__ __launch_bounds__(256) void softmax_kernel(float* __restrict__ sc)
{
    __shared__ float red[256];
    const int b = blockIdx.x;
    const int tid = threadIdx.x;
    float* row = sc + (size_t)b * Fdim;

    float v[16];
    float m = -INFINITY;
    #pragma unroll
    for (int i = 0; i < 16; ++i) {
        v[i] = row[tid + 256 * i];
        m = fmaxf(m, v[i]);
    }
    red[tid] = m;
    __syncthreads();
    for (int s = 128; s > 0; s >>= 1) {
        if (tid < s) red[tid] = fmaxf(red[tid], red[tid + s]);
        __syncthreads();
    }
    m = red[0];
    __syncthreads();

    float sum = 0.f;
    #pragma unroll
    for (int i = 0; i < 16; ++i) {
        v[i] = expf(v[i] - m);
        sum += v[i];
    }
    red[tid] = sum;
    __syncthreads();
    for (int s = 128; s > 0; s >>= 1) {
        if (tid < s) red[tid] += red[tid + s];
        __syncthreads();
    }
    const float inv = 1.f / red[0];
    #pragma unroll
    for (int i = 0; i < 16; ++i)
        row[tid + 256 * i] = v[i] * inv;
}

__global__ __launch_bounds__(256) void context_kernel(
    const float* __restrict__ feat, const float* __restrict__ wts,
    float* __restrict__ ctx)
{
    const int b  = blockIdx.y;
    const int fc = blockIdx.x;
    const int e  = threadIdx.x;

    const float* fp = feat + ((size_t)b * Fdim + (size_t)fc * 256) * Edim + e;
    const float* wp = wts + (size_t)b * Fdim + (size_t)fc * 256;

    float acc = 0.f;
    #pragma unroll 8
    for (int f = 0; f < 256; ++f)
        acc = fmaf(wp[f], fp[(size_t)f * Edim], acc);

    atomicAdd(&ctx[(size_t)b * Edim + e], acc);
}

// ---------------------------------------------------------------------------
extern "C" void kernel_launch(void* const* d_in, const int* in_sizes, int n_in,
                              void* d_out, int out_size, void* d_ws, size_t ws_size,
                              hipStream_t stream)
{
    const float* features = (const float*)d_in[0];
    const float* hidden   = (const float*)d_in[1];
    const float* W1w      = (const float*)d_in[2];
    const float* W1b      = (const float*)d_in[3];
    const float* W2w      = (const float*)d_in[4];
    const float* W2b      = (const float*)d_in[5];
    const float* Vw       = (const float*)d_in[6];
    const float* Vb       = (const float*)d_in[7];

    float* ctx = (float*)d_out;                       // (B,E)
    float* wts = (float*)d_out + (size_t)Bdim * Edim; // (B,F)

    // Workspace: cb (128 KiB) | W1Ts (256 KiB bf16 swizzled) | scr (1 MiB raw)
    float*          cb   = (float*)d_ws;
    unsigned short* W1Ts = (unsigned short*)((char*)d_ws + 131072);
    float*          scr  = (float*)((char*)d_ws + 131072 + 262144);
    const size_t NEED = 131072 + 262144 + (size_t)Bdim * Fdim * sizeof(float);
    const int mfma_ok = (ws_size >= NEED) ? 1 : 0;

    // prep: proj_h (128) + W1 transpose (32) + ctx zero (16) in one dispatch
    prep_kernel<<<176, 256, 0, stream>>>(hidden, W2w, W1b, W2b, cb,
                                         W1w, W1Ts, ctx, mfma_ok);

    if (mfma_ok) {
        dim3 sgrid(Fdim / 64, Bdim);        // (64, 64)
        score_mfma4_kernel<<<sgrid, 256, 0, stream>>>(features, W1Ts, Vw, Vb, cb, scr);
        dim3 cgrid(Fdim / 256, Bdim);       // (16, 64)
        ctxnorm_kernel<<<cgrid, 256, 0, stream>>>(features, scr, wts, ctx);
    } else {
        dim3 sgrid(Fdim / TFt, Bdim);
        score_kernel<<<sgrid, 256, 0, stream>>>(features, W1w, Vw, Vb, cb, wts);
        softmax_kernel<<<Bdim, 256, 0, stream>>>(wts);
        dim3 cgrid(16, Bdim);
        context_kernel<<<cgrid, 256, 0, stream>>>(features, wts, ctx);
    }
}

// Round 3
// 464.640 us; speedup vs baseline: 1.0359x; 1.0359x over previous
//
#include <hip/hip_runtime.h>
#include <cmath>

// Problem constants (from reference setup_inputs)
constexpr int Bdim = 64;
constexpr int Fdim = 4096;
constexpr int Edim = 256;
constexpr int Hdim = 512;
constexpr int Udim = 512;

typedef __attribute__((ext_vector_type(8))) short short8;   // 8 bf16 (16B)
typedef __attribute__((ext_vector_type(4))) float f32x4;

// ---------------------------------------------------------------------------
// Helpers
// ---------------------------------------------------------------------------
__device__ __forceinline__ unsigned short f2bf(float f) {
    unsigned int u = __float_as_uint(f);
    u += 0x7FFFu + ((u >> 16) & 1u);   // RNE; inputs finite
    return (unsigned short)(u >> 16);
}
__device__ __forceinline__ unsigned int pack2(float lo, float hi) {
    return (unsigned int)f2bf(lo) | ((unsigned int)f2bf(hi) << 16);
}
__device__ __forceinline__ float tanh_fast(float x) {
    float e = __expf(2.0f * x);
    return 1.0f - 2.0f * __builtin_amdgcn_rcpf(e + 1.0f);
}
// async global->LDS, 16B per lane; lds dest is wave-uniform base + lane*16
__device__ __forceinline__ void gload_lds16(const void* g, void* l) {
    __builtin_amdgcn_global_load_lds(
        (const __attribute__((address_space(1))) unsigned int*)g,
        (__attribute__((address_space(3))) unsigned int*)l, 16, 0, 0);
}

// ---------------------------------------------------------------------------
// Kernel 1 (fused prep): blocks 0..127   : cb[b][u] = W1b[u]+W2b[u]+hidden.W2
//                        blocks 128..159 : W1 -> transposed/swizzled bf16 W1Ts
//                        blocks 160..175 : zero ctx (needed by fallback path)
// ---------------------------------------------------------------------------
__global__ __launch_bounds__(256) void prep_kernel(
    const float* __restrict__ hidden, const float* __restrict__ W2,
    const float* __restrict__ W1b, const float* __restrict__ W2b,
    float* __restrict__ cb,
    const float* __restrict__ W1, unsigned short* __restrict__ Th,
    float* __restrict__ ctx, const int do_t)
{
    const int bid = blockIdx.x;
    const int tid = threadIdx.x;

    if (bid < 128) {
        // ---- proj_h ----
        const int b = bid >> 1;
        const int u = (bid & 1) * 256 + tid;
        const float* hb = hidden + (size_t)b * Hdim;
        float acc = 0.f;
        #pragma unroll 8
        for (int h = 0; h < Hdim; ++h)
            acc = fmaf(hb[h], W2[(size_t)h * Udim + u], acc);
        cb[(size_t)b * Udim + u] = acc + W1b[u] + W2b[u];
    } else if (bid < 160) {
        // ---- w1t: W1 (E,U) fp32 -> bf16 [U][E] with 16B-chunk XOR swizzle
        if (!do_t) return;
        __shared__ unsigned short sT[64][72];
        const int k  = bid - 128;            // 0..31 : (4 e-tiles) x (8 u-tiles)
        const int e0 = (k & 3) * 64, u0 = (k >> 2) * 64;
        const int ue = tid & 63, er = tid >> 6;
        #pragma unroll
        for (int it = 0; it < 16; ++it) {
            const int e = er + it * 4;
            sT[ue][e] = f2bf(W1[(size_t)(e0 + e) * Udim + u0 + ue]);
        }
        __syncthreads();
        const int ur = tid >> 2, cq = tid & 3;
        const int u = u0 + ur, s = u & 7;
        const int cA = (e0 >> 3) + cq * 2;   // global 16B-chunk index
        uint4 a  = *(const uint4*)&sT[ur][cq * 16];
        uint4 b2 = *(const uint4*)&sT[ur][cq * 16 + 8];
        unsigned short* dst = Th + (size_t)u * Edim;
        *(uint4*)(dst + ((cA ^ s) << 3))       = a;
        *(uint4*)(dst + (((cA + 1) ^ s) << 3)) = b2;
    } else {
        // ---- zero ctx ----
        const int idx = (bid - 160) * 256 + tid;
        ((float4*)ctx)[idx] = make_float4(0.f, 0.f, 0.f, 0.f);
    }
}

// ---------------------------------------------------------------------------
// Kernel 2 (dominant, flash-style): per block of 64 f-rows:
//   (a) raw scores via bf16 MFMA (16 u-passes, dbuf B via global_load_lds)
//   (b) block-local softmax stats (m,s) over the 64 rows
//   (c) partial context c[256] = sum_f exp(score-m)*feat[f,:], feat re-read
//       from L2/L3 (the block just streamed those 64 KB)
// Writes raw scores + (m, s, c) partials. NO second global features sweep.
// ---------------------------------------------------------------------------
__global__ __launch_bounds__(256, 4) void score_mfma4_kernel(
    const float* __restrict__ feat,            // [B][F][E] fp32
    const unsigned short* __restrict__ W1Ts,   // [U][E] bf16, chunk-swizzled
    const float* __restrict__ Vw, const float* __restrict__ Vb,
    const float* __restrict__ cb, float* __restrict__ scr,
    float* __restrict__ pm, float* __restrict__ ps, float* __restrict__ pc)
{
    __shared__ unsigned short lds[16896];   // 33,792 B: A-scratch / B dbuf / C scratch

    const int b    = blockIdx.y;
    const int fc   = blockIdx.x;        // 0..63
    const int f0   = fc * 64;
    const int tid  = threadIdx.x;
    const int lane = tid & 63;
    const int w    = tid >> 6;          // wave id; 16 f-rows each
    const int ln15 = lane & 15;
    const int kq   = lane >> 4;         // 0..3
    const int swz  = ln15 & 7;

    // ---- Phase A: stage+convert 16 f-rows into af[8] (32 VGPRs) ----
    short8 af[8];
    {
        unsigned short* sAw = lds + w * 4224;   // 16 rows x 264 shorts per wave
        const float* gA = feat + ((size_t)(b * Fdim + f0 + w * 16)) * Edim;
        #pragma unroll
        for (int r = 0; r < 16; ++r) {
            float4 v = *(const float4*)(gA + (size_t)r * Edim + lane * 4);
            uint2 p; p.x = pack2(v.x, v.y); p.y = pack2(v.z, v.w);
            *(uint2*)&sAw[r * 264 + lane * 4] = p;
        }
        #pragma unroll
        for (int k8 = 0; k8 < 8; ++k8)
            af[k8] = *(const short8*)&sAw[ln15 * 264 + k8 * 32 + kq * 8];
    }
    __syncthreads();   // all waves done with A scratch before B overwrites it

    float sacc[4] = {};
    const float* cbB = cb + (size_t)b * Udim;

    // ---- prologue: stage pass 0 (u-rows 0..31, 16 KB) into buf0 ----
    {
        const char* gB = (const char*)W1Ts;
        #pragma unroll
        for (int t = 0; t < 4; ++t) {
            const int chunk = w * 4 + t;   // 16 x 1 KB
            gload_lds16(gB + (size_t)chunk * 1024 + lane * 16,
                        (char*)lds + chunk * 1024);
        }
    }
    __syncthreads();

    for (int p = 0; p < 16; ++p) {
        // issue-early prefetch of next window into the other buffer
        if (p < 15) {
            const char* gB = (const char*)(W1Ts + (size_t)(p + 1) * 32 * Edim);
            char* lb = (char*)lds + ((p + 1) & 1) * 16384;
            #pragma unroll
            for (int t = 0; t < 4; ++t) {
                const int chunk = w * 4 + t;
                gload_lds16(gB + (size_t)chunk * 1024 + lane * 16,
                            lb + chunk * 1024);
            }
        }

        const unsigned short* bw = lds + (p & 1) * 8192;   // current window
        const int ub = p * 32;
        const float cu0 = cbB[ub + ln15],     cu1 = cbB[ub + 16 + ln15];
        const float vv0 = Vw[ub + ln15],      vv1 = Vw[ub + 16 + ln15];
        f32x4 acc0 = {}, acc1 = {};
        #pragma unroll
        for (int k8 = 0; k8 < 8; ++k8) {
            const int co = ((k8 * 4 + kq) ^ swz) * 8;   // swizzled chunk
            short8 b0 = *(const short8*)&bw[ln15 * 256 + co];
            short8 b1 = *(const short8*)&bw[(16 + ln15) * 256 + co];
            acc0 = __builtin_amdgcn_mfma_f32_16x16x32_bf16(af[k8], b0, acc0, 0, 0, 0);
            acc1 = __builtin_amdgcn_mfma_f32_16x16x32_bf16(af[k8], b1, acc1, 0, 0, 0);
        }
        // fused epilogue: tanh + V-dot into running per-f partials
        #pragma unroll
        for (int r = 0; r < 4; ++r)
            sacc[r] += tanh_fast(acc0[r] + cu0) * vv0
                     + tanh_fast(acc1[r] + cu1) * vv1;

        if (p < 15) __syncthreads();   // reads done before buf reuse; drains
    }                                  // prefetch (covered by compute above)

    // ---- Phase B: scores -> LDS + global; block-local softmax stats ----
    // LDS reuse: bytes 0..511 (sF/wl) and 1024..5119 (sred) live in buf0,
    // whose last reads drained at the p==14 barrier (p==15 reads buf1).
    float* sF = (float*)lds;                       // 64 scores
    float* wl = (float*)lds + 64;                  // 64 weights
    float4* sred = (float4*)((char*)lds + 1024);   // 256 float4

    const float vb = Vb[0];
    #pragma unroll
    for (int r = 0; r < 4; ++r) {
        float s = sacc[r];
        s += __shfl_xor(s, 1);
        s += __shfl_xor(s, 2);
        s += __shfl_xor(s, 4);
        s += __shfl_xor(s, 8);
        if (ln15 == 0) {
            const int fr = w * 16 + kq * 4 + r;
            const float sv = s + vb;
            scr[(size_t)b * Fdim + f0 + fr] = sv;
            sF[fr] = sv;
        }
    }
    __syncthreads();

    if (tid < 64) {   // wave 0: stats + local weights
        const float sc = sF[tid];
        float m = sc;
        #pragma unroll
        for (int off = 1; off < 64; off <<= 1)
            m = fmaxf(m, __shfl_xor(m, off));
        const float wv = expf(sc - m);
        float sm = wv;
        #pragma unroll
        for (int off = 1; off < 64; off <<= 1)
            sm += __shfl_xor(sm, off);
        wl[tid] = wv;
        if (tid == 0) {
            pm[b * 64 + fc] = m;
            ps[b * 64 + fc] = sm;
        }
    }
    __syncthreads();

    // ---- Phase C: partial context from L2/L3-hot features ----
    const int e4 = tid & 63;   // float4 column
    const int fg = tid >> 6;   // f-row group (0..3)
    const float4* fp = (const float4*)(feat + ((size_t)b * Fdim + f0) * Edim);

    float4 a = make_float4(0.f, 0.f, 0.f, 0.f);
    #pragma unroll
    for (int i = 0; i < 16; ++i) {
        const int f = i * 4 + fg;
        const float4 fv = fp[(size_t)f * 64 + e4];
        const float wv = wl[f];
        a.x = fmaf(wv, fv.x, a.x);
        a.y = fmaf(wv, fv.y, a.y);
        a.z = fmaf(wv, fv.z, a.z);
        a.w = fmaf(wv, fv.w, a.w);
    }
    sred[tid] = a;
    __syncthreads();

    if (fg == 0) {
        const float4 r0 = sred[e4];
        const float4 r1 = sred[64 + e4];
        const float4 r2 = sred[128 + e4];
        const float4 r3 = sred[192 + e4];
        float4 o;
        o.x = r0.x + r1.x + r2.x + r3.x;
        o.y = r0.y + r1.y + r2.y + r3.y;
        o.z = r0.z + r1.z + r2.z + r3.z;
        o.w = r0.w + r1.w + r2.w + r3.w;
        *(float4*)&pc[((size_t)b * 64 + fc) * 256 + e4 * 4] = o;
    }
}

// ---------------------------------------------------------------------------
// Kernel 3: merge 64 partials per b (online-softmax combine), write ctx and
// normalized weights. 64 blocks; ~35 KB traffic each.
// ---------------------------------------------------------------------------
__global__ __launch_bounds__(256) void merge_kernel(
    const float* __restrict__ scr, const float* __restrict__ pm,
    const float* __restrict__ ps, const float* __restrict__ pc,
    float* __restrict__ wts, float* __restrict__ ctx)
{
    __shared__ float sscale[64];
    __shared__ float sms[2];

    const int b   = blockIdx.x;
    const int tid = threadIdx.x;

    if (tid < 64) {
        const float mi = pm[b * 64 + tid];
        float m = mi;
        #pragma unroll
        for (int off = 1; off < 64; off <<= 1)
            m = fmaxf(m, __shfl_xor(m, off));
        const float sc = expf(mi - m);
        float s = ps[b * 64 + tid] * sc;
        #pragma unroll
        for (int off = 1; off < 64; off <<= 1)
            s += __shfl_xor(s, off);
        sscale[tid] = sc;
        if (tid == 0) { sms[0] = m; sms[1] = 1.0f / s; }
    }
    __syncthreads();
    const float m   = sms[0];
    const float inv = sms[1];

    // context: thread t owns e = t
    {
        float c = 0.f;
        const float* p = pc + (size_t)b * 64 * 256 + tid;
        #pragma unroll 8
        for (int i = 0; i < 64; ++i)
            c = fmaf(p[(size_t)i * 256], sscale[i], c);
        ctx[(size_t)b * Edim + tid] = c * inv;
    }

    // normalized weights from raw scores
    const float* row  = scr + (size_t)b * Fdim;
    float*       wrow = wts + (size_t)b * Fdim;
    #pragma unroll
    for (int i = 0; i < 16; ++i) {
        const float v = row[tid + 256 * i];
        wrow[tid + 256 * i] = expf(v - m) * inv;
    }
}

// ---------------------------------------------------------------------------
// Fallback path (ws too small): fp32 score -> in-place softmax -> context
// ---------------------------------------------------------------------------
constexpr int TFt = 64;
constexpr int TUt = 64;
constexpr int LDR = Edim + 4;

__global__ __launch_bounds__(256) void score_kernel(
    const float* __restrict__ feat, const float* __restrict__ W1,
    const float* __restrict__ Vw, const float* __restrict__ Vb,
    const float* __restrict__ cb, float* __restrict__ scores)
{
    __shared__ float sA[TFt * LDR];
    __shared__ float sW[TUt * LDR];

    const int b   = blockIdx.y;
    const int f0  = blockIdx.x * TFt;
    const int tid = threadIdx.x;
    const int tf  = tid >> 4;
    const int tu  = tid & 15;

    {
        const float4* gA = (const float4*)(feat + ((size_t)b * Fdim + f0) * Edim);
        #pragma unroll
        for (int it = 0; it < 16; ++it) {
            const int i = tid + it * 256;
            const int f = i >> 6;
            const int qq = i & 63;
            const float4 v = gA[i];
            *(float4*)&sA[f * LDR + 4 * qq] = v;
        }
    }

    float sacc[4] = {0.f, 0.f, 0.f, 0.f};
    const float* cbb = cb + (size_t)b * Udim;

    for (int uc = 0; uc < Udim; uc += TUt) {
        __syncthreads();
        #pragma unroll
        for (int it = 0; it < 16; ++it) {
            const int i = tid + it * 256;
            const int e = i >> 4;
            const int qq = i & 15;
            const float4 v = *(const float4*)(W1 + (size_t)e * Udim + uc + 4 * qq);
            sW[(4 * qq + 0) * LDR + e] = v.x;
            sW[(4 * qq + 1) * LDR + e] = v.y;
            sW[(4 * qq + 2) * LDR + e] = v.z;
            sW[(4 * qq + 3) * LDR + e] = v.w;
        }
        __syncthreads();

        float acc[4][4] = {};
        #pragma unroll 4
        for (int e = 0; e < Edim; e += 4) {
            float4 a0 = *(const float4*)&sA[(tf +  0) * LDR + e];
            float4 a1 = *(const float4*)&sA[(tf + 16) * LDR + e];
            float4 a2 = *(const float4*)&sA[(tf + 32) * LDR + e];
            float4 a3 = *(const float4*)&sA[(tf + 48) * LDR + e];
            float4 w0 = *(const float4*)&sW[(tu +  0) * LDR + e];
            float4 w1 = *(const float4*)&sW[(tu + 16) * LDR + e];
            float4 w2 = *(const float4*)&sW[(tu + 32) * LDR + e];
            float4 w3 = *(const float4*)&sW[(tu + 48) * LDR + e];
            #define FMA4(i, j, A, W)                         \
                acc[i][j] = fmaf(A.x, W.x, acc[i][j]);       \
                acc[i][j] = fmaf(A.y, W.y, acc[i][j]);       \
                acc[i][j] = fmaf(A.z, W.z, acc[i][j]);       \
                acc[i][j] = fmaf(A.w, W.w, acc[i][j]);
            FMA4(0,0,a0,w0) FMA4(0,1,a0,w1) FMA4(0,2,a0,w2) FMA4(0,3,a0,w3)
            FMA4(1,0,a1,w0) FMA4(1,1,a1,w1) FMA4(1,2,a1,w2) FMA4(1,3,a1,w3)
            FMA4(2,0,a2,w0) FMA4(2,1,a2,w1) FMA4(2,2,a2,w2) FMA4(2,3,a2,w3)
            FMA4(3,0,a3,w0) FMA4(3,1,a3,w1) FMA4(3,2,a3,w2) FMA4(3,3,a3,w3)
            #undef FMA4
        }

        #pragma unroll
        for (int j = 0; j < 4; ++j) {
            const int u = uc + tu + 16 * j;
            const float vw = Vw[u];
            const float cuv = cbb[u];
            #pragma unroll
            for (int i = 0; i < 4; ++i)
                sacc[i] = fmaf(tanhf(acc[i][j] + cuv), vw, sacc[i]);
        }
    }

    const float vb = Vb[0];
    #pragma unroll
    for (int i = 0; i < 4; ++i) {
        float s = sacc[i];
        s += __shfl_xor(s, 1);
        s += __shfl_xor(s, 2);
        s += __shfl_xor(s, 4);
        s += __shfl_xor(s, 8);
        if (tu == 0)
            scores[(size_t)b * Fdim + f0 + tf + 16 * i] = s + vb;
    }
}

__global__ __launch_bounds__(256) void softmax_kernel(float* __restrict__ sc)
{
    __shared__ float red[256];
    const int b = blockIdx.x;
    const int tid = threadIdx.x;
    float* row = sc + (size_t)b * Fdim;

    float v[16];
    float m = -INFINITY;
    #pragma unroll
    for (int i = 0; i < 16; ++i) {
        v[i] = row[tid + 256 * i];
        m = fmaxf(m, v[i]);
    }
    red[tid] = m;
    __syncthreads();
    for (int s = 128; s > 0; s >>= 1) {
        if (tid < s) red[tid] = fmaxf(red[tid], red[tid + s]);
        __syncthreads();
    }
    m = red[0];
    __syncthreads();

    float sum = 0.f;
    #pragma unroll
    for (int i = 0; i < 16; ++i) {
        v[i] = expf(v[i] - m);
        sum += v[i];
    }
    red[tid] = sum;
    __syncthreads();
    for (int s = 128; s > 0; s >>= 1) {
        if (tid < s) red[tid] += red[tid + s];
        __syncthreads();
    }
    const float inv = 1.f / red[0];
    #pragma unroll
    for (int i = 0; i < 16; ++i)
        row[tid + 256 * i] = v[i] * inv;
}

__global__ __launch_bounds__(256) void context_kernel(
    const float* __restrict__ feat, const float* __restrict__ wts,
    float* __restrict__ ctx)
{
    const int b  = blockIdx.y;
    const int fc = blockIdx.x;
    const int e  = threadIdx.x;

    const float* fp = feat + ((size_t)b * Fdim + (size_t)fc * 256) * Edim + e;
    const float* wp = wts + (size_t)b * Fdim + (size_t)fc * 256;

    float acc = 0.f;
    #pragma unroll 8
    for (int f = 0; f < 256; ++f)
        acc = fmaf(wp[f], fp[(size_t)f * Edim], acc);

    atomicAdd(&ctx[(size_t)b * Edim + e], acc);
}

// ---------------------------------------------------------------------------
extern "C" void kernel_launch(void* const* d_in, const int* in_sizes, int n_in,
                              void* d_out, int out_size, void* d_ws, size_t ws_size,
                              hipStream_t stream)
{
    const float* features = (const float*)d_in[0];
    const float* hidden   = (const float*)d_in[1];
    const float* W1w      = (const float*)d_in[2];
    const float* W1b      = (const float*)d_in[3];
    const float* W2w      = (const float*)d_in[4];
    const float* W2b      = (const float*)d_in[5];
    const float* Vw       = (const float*)d_in[6];
    const float* Vb       = (const float*)d_in[7];

    float* ctx = (float*)d_out;                       // (B,E)
    float* wts = (float*)d_out + (size_t)Bdim * Edim; // (B,F)

    // Workspace layout:
    //   cb    128 KiB | W1Ts 256 KiB | scr 1 MiB | pm 16 KiB | ps 16 KiB
    //   pc    4 MiB (64 b x 64 chunks x 256 e)
    float*          cb   = (float*)d_ws;
    unsigned short* W1Ts = (unsigned short*)((char*)d_ws + 131072);
    float*          scr  = (float*)((char*)d_ws + 393216);
    float*          pm   = (float*)((char*)d_ws + 1441792);
    float*          ps   = (float*)((char*)d_ws + 1458176);
    float*          pc   = (float*)((char*)d_ws + 1474560);
    const size_t NEED = 1474560 + (size_t)Bdim * 64 * Edim * sizeof(float);
    const int mfma_ok = (ws_size >= NEED) ? 1 : 0;

    // prep: proj_h (128) + W1 transpose (32) + ctx zero (16) in one dispatch
    prep_kernel<<<176, 256, 0, stream>>>(hidden, W2w, W1b, W2b, cb,
                                         W1w, W1Ts, ctx, mfma_ok);

    if (mfma_ok) {
        dim3 sgrid(Fdim / 64, Bdim);        // (64, 64)
        score_mfma4_kernel<<<sgrid, 256, 0, stream>>>(features, W1Ts, Vw, Vb, cb,
                                                      scr, pm, ps, pc);
        merge_kernel<<<Bdim, 256, 0, stream>>>(scr, pm, ps, pc, wts, ctx);
    } else {
        dim3 sgrid(Fdim / TFt, Bdim);
        score_kernel<<<sgrid, 256, 0, stream>>>(features, W1w, Vw, Vb, cb, wts);
        softmax_kernel<<<Bdim, 256, 0, stream>>>(wts);
        dim3 cgrid(16, Bdim);
        context_kernel<<<cgrid, 256, 0, stream>>>(features, wts, ctx);
    }
}

// Round 4
// 459.291 us; speedup vs baseline: 1.0479x; 1.0116x over previous
//
#include <hip/hip_runtime.h>
#include <cmath>

// Problem constants (from reference setup_inputs)
constexpr int Bdim = 64;
constexpr int Fdim = 4096;
constexpr int Edim = 256;
constexpr int Hdim = 512;
constexpr int Udim = 512;

typedef __attribute__((ext_vector_type(8))) short short8;   // 8 bf16 (16B)
typedef __attribute__((ext_vector_type(4))) float f32x4;

// ---------------------------------------------------------------------------
// Helpers
// ---------------------------------------------------------------------------
__device__ __forceinline__ unsigned short f2bf(float f) {
    unsigned int u = __float_as_uint(f);
    u += 0x7FFFu + ((u >> 16) & 1u);   // RNE; inputs finite
    return (unsigned short)(u >> 16);
}
__device__ __forceinline__ unsigned int pack2(float lo, float hi) {
    return (unsigned int)f2bf(lo) | ((unsigned int)f2bf(hi) << 16);
}
__device__ __forceinline__ float tanh_fast(float x) {
    float e = __expf(2.0f * x);
    return 1.0f - 2.0f * __builtin_amdgcn_rcpf(e + 1.0f);
}
// async global->LDS, 16B per lane; lds dest is wave-uniform base + lane*16
__device__ __forceinline__ void gload_lds16(const void* g, void* l) {
    __builtin_amdgcn_global_load_lds(
        (const __attribute__((address_space(1))) unsigned int*)g,
        (__attribute__((address_space(3))) unsigned int*)l, 16, 0, 0);
}

// ---------------------------------------------------------------------------
// Kernel 1 (fused prep): blocks 0..127   : cb[b][u] = W1b[u]+W2b[u]+hidden.W2
//                        blocks 128..159 : W1 -> transposed/swizzled bf16 W1Ts
//                        blocks 160..175 : zero ctx (needed by fallback path)
// ---------------------------------------------------------------------------
__global__ __launch_bounds__(256) void prep_kernel(
    const float* __restrict__ hidden, const float* __restrict__ W2,
    const float* __restrict__ W1b, const float* __restrict__ W2b,
    float* __restrict__ cb,
    const float* __restrict__ W1, unsigned short* __restrict__ Th,
    float* __restrict__ ctx, const int do_t)
{
    const int bid = blockIdx.x;
    const int tid = threadIdx.x;

    if (bid < 128) {
        // ---- proj_h ----
        const int b = bid >> 1;
        const int u = (bid & 1) * 256 + tid;
        const float* hb = hidden + (size_t)b * Hdim;
        float acc = 0.f;
        #pragma unroll 8
        for (int h = 0; h < Hdim; ++h)
            acc = fmaf(hb[h], W2[(size_t)h * Udim + u], acc);
        cb[(size_t)b * Udim + u] = acc + W1b[u] + W2b[u];
    } else if (bid < 160) {
        // ---- w1t: W1 (E,U) fp32 -> bf16 [U][E] with 16B-chunk XOR swizzle
        if (!do_t) return;
        __shared__ unsigned short sT[64][72];
        const int k  = bid - 128;            // 0..31 : (4 e-tiles) x (8 u-tiles)
        const int e0 = (k & 3) * 64, u0 = (k >> 2) * 64;
        const int ue = tid & 63, er = tid >> 6;
        #pragma unroll
        for (int it = 0; it < 16; ++it) {
            const int e = er + it * 4;
            sT[ue][e] = f2bf(W1[(size_t)(e0 + e) * Udim + u0 + ue]);
        }
        __syncthreads();
        const int ur = tid >> 2, cq = tid & 3;
        const int u = u0 + ur, s = u & 7;
        const int cA = (e0 >> 3) + cq * 2;   // global 16B-chunk index
        uint4 a  = *(const uint4*)&sT[ur][cq * 16];
        uint4 b2 = *(const uint4*)&sT[ur][cq * 16 + 8];
        unsigned short* dst = Th + (size_t)u * Edim;
        *(uint4*)(dst + ((cA ^ s) << 3))       = a;
        *(uint4*)(dst + (((cA + 1) ^ s) << 3)) = b2;
    } else {
        // ---- zero ctx ----
        const int idx = (bid - 160) * 256 + tid;
        ((float4*)ctx)[idx] = make_float4(0.f, 0.f, 0.f, 0.f);
    }
}

// ---------------------------------------------------------------------------
// Kernel 2 (dominant, flash-style): per block of 128 f-rows:
//   (a) raw scores via bf16 MFMA — af[2][8] per wave (32 rows), 16 u-passes
//       of 32 rows (16 KB) double-buffered via global_load_lds. 32 MFMA per
//       16 ds_read_b128 per pass (2:1) -> LDS pipe under the HBM budget.
//   (b) block-local softmax stats (m,s) over its 128 rows
//   (c) partial context c[256] = sum_f exp(score-m)*feat[f,:] from L2/L3-hot
//       features (the block just streamed those 128 KB)
// Writes raw scores + (m, s, c) partials. NO second global features sweep.
// ---------------------------------------------------------------------------
__global__ __launch_bounds__(256, 4) void score_mfma4_kernel(
    const float* __restrict__ feat,            // [B][F][E] fp32
    const unsigned short* __restrict__ W1Ts,   // [U][E] bf16, chunk-swizzled
    const float* __restrict__ Vw, const float* __restrict__ Vb,
    const float* __restrict__ cb, float* __restrict__ scr,
    float* __restrict__ pm, float* __restrict__ ps, float* __restrict__ pc)
{
    __shared__ unsigned short lds[16896];   // 33,792 B: A-scratch / B dbuf / C scratch

    const int b    = blockIdx.y;
    const int fc   = blockIdx.x;        // 0..31
    const int f0   = fc * 128;
    const int tid  = threadIdx.x;
    const int lane = tid & 63;
    const int w    = tid >> 6;          // wave id; 32 f-rows each
    const int ln15 = lane & 15;
    const int kq   = lane >> 4;         // 0..3
    const int swz  = ln15 & 7;

    // ---- Phase A: stage+convert 32 f-rows into af[2][8] (64 VGPRs) ----
    short8 af[2][8];
    {
        unsigned short* sAw = lds + w * 4224;   // 16 rows x 264 shorts per wave
        const float* gA = feat + ((size_t)(b * Fdim + f0 + w * 32)) * Edim;
        #pragma unroll
        for (int h = 0; h < 2; ++h) {
            #pragma unroll
            for (int r = 0; r < 16; ++r) {
                float4 v = *(const float4*)(gA + (size_t)(h * 16 + r) * Edim + lane * 4);
                uint2 p; p.x = pack2(v.x, v.y); p.y = pack2(v.z, v.w);
                *(uint2*)&sAw[r * 264 + lane * 4] = p;
            }
            #pragma unroll
            for (int k8 = 0; k8 < 8; ++k8)
                af[h][k8] = *(const short8*)&sAw[ln15 * 264 + k8 * 32 + kq * 8];
        }
    }
    __syncthreads();   // all waves done with A scratch before B overwrites it

    float sacc[2][4] = {};   // [mi][r]
    const float* cbB = cb + (size_t)b * Udim;

    // ---- prologue: stage pass 0 (u-rows 0..31, 16 KB) into buf0 ----
    {
        const char* gB = (const char*)W1Ts;
        #pragma unroll
        for (int t = 0; t < 4; ++t) {
            const int chunk = w * 4 + t;   // 16 x 1 KB
            gload_lds16(gB + (size_t)chunk * 1024 + lane * 16,
                        (char*)lds + chunk * 1024);
        }
    }
    __syncthreads();

    for (int p = 0; p < 16; ++p) {
        // issue-early prefetch of next window into the other buffer
        if (p < 15) {
            const char* gB = (const char*)(W1Ts + (size_t)(p + 1) * 32 * Edim);
            char* lb = (char*)lds + ((p + 1) & 1) * 16384;
            #pragma unroll
            for (int t = 0; t < 4; ++t) {
                const int chunk = w * 4 + t;
                gload_lds16(gB + (size_t)chunk * 1024 + lane * 16,
                            lb + chunk * 1024);
            }
        }

        const unsigned short* bw = lds + (p & 1) * 8192;   // current window
        const int ub = p * 32;
        const float cu0 = cbB[ub + ln15],     cu1 = cbB[ub + 16 + ln15];
        const float vv0 = Vw[ub + ln15],      vv1 = Vw[ub + 16 + ln15];
        f32x4 acc[2][2] = {};
        #pragma unroll
        for (int k8 = 0; k8 < 8; ++k8) {
            const int co = ((k8 * 4 + kq) ^ swz) * 8;   // swizzled chunk
            short8 b0 = *(const short8*)&bw[ln15 * 256 + co];
            short8 b1 = *(const short8*)&bw[(16 + ln15) * 256 + co];
            #pragma unroll
            for (int mi = 0; mi < 2; ++mi) {
                acc[mi][0] = __builtin_amdgcn_mfma_f32_16x16x32_bf16(
                    af[mi][k8], b0, acc[mi][0], 0, 0, 0);
                acc[mi][1] = __builtin_amdgcn_mfma_f32_16x16x32_bf16(
                    af[mi][k8], b1, acc[mi][1], 0, 0, 0);
            }
        }
        // fused epilogue: tanh + V-dot into running per-f partials
        #pragma unroll
        for (int mi = 0; mi < 2; ++mi)
            #pragma unroll
            for (int r = 0; r < 4; ++r)
                sacc[mi][r] += tanh_fast(acc[mi][0][r] + cu0) * vv0
                             + tanh_fast(acc[mi][1][r] + cu1) * vv1;

        if (p < 15) __syncthreads();   // reads done before buf reuse; drains
    }                                  // prefetch (covered by compute above)

    // ---- Phase B: scores -> LDS + global; block-local softmax stats ----
    // LDS reuse: sF/wl (bytes 0..1023) and sred (1024..5119) live in buf0;
    // pass 15 reads buf1 only, so no hazard with in-flight ds_reads.
    float* sF = (float*)lds;                       // 128 scores
    float* wl = (float*)lds + 128;                 // 128 weights
    float4* sred = (float4*)((char*)lds + 1024);   // 256 float4

    const float vb = Vb[0];
    #pragma unroll
    for (int mi = 0; mi < 2; ++mi)
        #pragma unroll
        for (int r = 0; r < 4; ++r) {
            float s = sacc[mi][r];
            s += __shfl_xor(s, 1);
            s += __shfl_xor(s, 2);
            s += __shfl_xor(s, 4);
            s += __shfl_xor(s, 8);
            if (ln15 == 0) {
                const int fr = w * 32 + mi * 16 + kq * 4 + r;
                const float sv = s + vb;
                scr[(size_t)b * Fdim + f0 + fr] = sv;
                sF[fr] = sv;
            }
        }
    __syncthreads();

    if (tid < 64) {   // wave 0: stats + local weights over 128 rows
        const float s0 = sF[tid];
        const float s1 = sF[64 + tid];
        float m = fmaxf(s0, s1);
        #pragma unroll
        for (int off = 1; off < 64; off <<= 1)
            m = fmaxf(m, __shfl_xor(m, off));
        const float w0 = expf(s0 - m);
        const float w1 = expf(s1 - m);
        float sm = w0 + w1;
        #pragma unroll
        for (int off = 1; off < 64; off <<= 1)
            sm += __shfl_xor(sm, off);
        wl[tid]      = w0;
        wl[64 + tid] = w1;
        if (tid == 0) {
            pm[b * 32 + fc] = m;
            ps[b * 32 + fc] = sm;
        }
    }
    __syncthreads();

    // ---- Phase C: partial context from L2/L3-hot features (128 rows) ----
    const int e4 = tid & 63;   // float4 column
    const int fg = tid >> 6;   // f-row group (0..3)
    const float4* fp = (const float4*)(feat + ((size_t)b * Fdim + f0) * Edim);

    float4 a = make_float4(0.f, 0.f, 0.f, 0.f);
    #pragma unroll 8
    for (int i = 0; i < 32; ++i) {
        const int f = i * 4 + fg;
        const float4 fv = fp[(size_t)f * 64 + e4];
        const float wv = wl[f];
        a.x = fmaf(wv, fv.x, a.x);
        a.y = fmaf(wv, fv.y, a.y);
        a.z = fmaf(wv, fv.z, a.z);
        a.w = fmaf(wv, fv.w, a.w);
    }
    sred[tid] = a;
    __syncthreads();

    if (fg == 0) {
        const float4 r0 = sred[e4];
        const float4 r1 = sred[64 + e4];
        const float4 r2 = sred[128 + e4];
        const float4 r3 = sred[192 + e4];
        float4 o;
        o.x = r0.x + r1.x + r2.x + r3.x;
        o.y = r0.y + r1.y + r2.y + r3.y;
        o.z = r0.z + r1.z + r2.z + r3.z;
        o.w = r0.w + r1.w + r2.w + r3.w;
        *(float4*)&pc[((size_t)b * 32 + fc) * 256 + e4 * 4] = o;
    }
}

// ---------------------------------------------------------------------------
// Kernel 3: merge 32 partials per b (online-softmax combine), write ctx and
// normalized weights. 64 blocks; ~20 KB traffic each.
// ---------------------------------------------------------------------------
__global__ __launch_bounds__(256) void merge_kernel(
    const float* __restrict__ scr, const float* __restrict__ pm,
    const float* __restrict__ ps, const float* __restrict__ pc,
    float* __restrict__ wts, float* __restrict__ ctx)
{
    __shared__ float sscale[32];
    __shared__ float sms[2];

    const int b   = blockIdx.x;
    const int tid = threadIdx.x;

    if (tid < 64) {
        const int c  = tid & 31;
        const bool lo = tid < 32;
        const float mi = lo ? pm[b * 32 + c] : -INFINITY;
        float m = mi;
        #pragma unroll
        for (int off = 1; off < 64; off <<= 1)
            m = fmaxf(m, __shfl_xor(m, off));
        const float sc = lo ? expf(mi - m) : 0.f;
        float s = lo ? ps[b * 32 + c] * sc : 0.f;
        #pragma unroll
        for (int off = 1; off < 64; off <<= 1)
            s += __shfl_xor(s, off);
        if (lo) sscale[c] = sc;
        if (tid == 0) { sms[0] = m; sms[1] = 1.0f / s; }
    }
    __syncthreads();
    const float m   = sms[0];
    const float inv = sms[1];

    // context: thread t owns e = t
    {
        float c = 0.f;
        const float* p = pc + (size_t)b * 32 * 256 + tid;
        #pragma unroll 8
        for (int i = 0; i < 32; ++i)
            c = fmaf(p[(size_t)i * 256], sscale[i], c);
        ctx[(size_t)b * Edim + tid] = c * inv;
    }

    // normalized weights from raw scores
    const float* row  = scr + (size_t)b * Fdim;
    float*       wrow = wts + (size_t)b * Fdim;
    #pragma unroll
    for (int i = 0; i < 16; ++i) {
        const float v = row[tid + 256 * i];
        wrow[tid + 256 * i] = expf(v - m) * inv;
    }
}

// ---------------------------------------------------------------------------
// Fallback path (ws too small): fp32 score -> in-place softmax -> context
// ---------------------------------------------------------------------------
constexpr int TFt = 64;
constexpr int TUt = 64;
constexpr int LDR = Edim + 4;

__global__ __launch_bounds__(256) void score_kernel(
    const float* __restrict__ feat, const float* __restrict__ W1,
    const float* __restrict__ Vw, const float* __restrict__ Vb,
    const float* __restrict__ cb, float* __restrict__ scores)
{
    __shared__ float sA[TFt * LDR];
    __shared__ float sW[TUt * LDR];

    const int b   = blockIdx.y;
    const int f0  = blockIdx.x * TFt;
    const int tid = threadIdx.x;
    const int tf  = tid >> 4;
    const int tu  = tid & 15;

    {
        const float4* gA = (const float4*)(feat + ((size_t)b * Fdim + f0) * Edim);
        #pragma unroll
        for (int it = 0; it < 16; ++it) {
            const int i = tid + it * 256;
            const int f = i >> 6;
            const int qq = i & 63;
            const float4 v = gA[i];
            *(float4*)&sA[f * LDR + 4 * qq] = v;
        }
    }

    float sacc[4] = {0.f, 0.f, 0.f, 0.f};
    const float* cbb = cb + (size_t)b * Udim;

    for (int uc = 0; uc < Udim; uc += TUt) {
        __syncthreads();
        #pragma unroll
        for (int it = 0; it < 16; ++it) {
            const int i = tid + it * 256;
            const int e = i >> 4;
            const int qq = i & 15;
            const float4 v = *(const float4*)(W1 + (size_t)e * Udim + uc + 4 * qq);
            sW[(4 * qq + 0) * LDR + e] = v.x;
            sW[(4 * qq + 1) * LDR + e] = v.y;
            sW[(4 * qq + 2) * LDR + e] = v.z;
            sW[(4 * qq + 3) * LDR + e] = v.w;
        }
        __syncthreads();

        float acc[4][4] = {};
        #pragma unroll 4
        for (int e = 0; e < Edim; e += 4) {
            float4 a0 = *(const float4*)&sA[(tf +  0) * LDR + e];
            float4 a1 = *(const float4*)&sA[(tf + 16) * LDR + e];
            float4 a2 = *(const float4*)&sA[(tf + 32) * LDR + e];
            float4 a3 = *(const float4*)&sA[(tf + 48) * LDR + e];
            float4 w0 = *(const float4*)&sW[(tu +  0) * LDR + e];
            float4 w1 = *(const float4*)&sW[(tu + 16) * LDR + e];
            float4 w2 = *(const float4*)&sW[(tu + 32) * LDR + e];
            float4 w3 = *(const float4*)&sW[(tu + 48) * LDR + e];
            #define FMA4(i, j, A, W)                         \
                acc[i][j] = fmaf(A.x, W.x, acc[i][j]);       \
                acc[i][j] = fmaf(A.y, W.y, acc[i][j]);       \
                acc[i][j] = fmaf(A.z, W.z, acc[i][j]);       \
                acc[i][j] = fmaf(A.w, W.w, acc[i][j]);
            FMA4(0,0,a0,w0) FMA4(0,1,a0,w1) FMA4(0,2,a0,w2) FMA4(0,3,a0,w3)
            FMA4(1,0,a1,w0) FMA4(1,1,a1,w1) FMA4(1,2,a1,w2) FMA4(1,3,a1,w3)
            FMA4(2,0,a2,w0) FMA4(2,1,a2,w1) FMA4(2,2,a2,w2) FMA4(2,3,a2,w3)
            FMA4(3,0,a3,w0) FMA4(3,1,a3,w1) FMA4(3,2,a3,w2) FMA4(3,3,a3,w3)
            #undef FMA4
        }

        #pragma unroll
        for (int j = 0; j < 4; ++j) {
            const int u = uc + tu + 16 * j;
            const float vw = Vw[u];
            const float cuv = cbb[u];
            #pragma unroll
            for (int i = 0; i < 4; ++i)
                sacc[i] = fmaf(tanhf(acc[i][j] + cuv), vw, sacc[i]);
        }
    }

    const float vb = Vb[0];
    #pragma unroll
    for (int i = 0; i < 4; ++i) {
        float s = sacc[i];
        s += __shfl_xor(s, 1);
        s += __shfl_xor(s, 2);
        s += __shfl_xor(s, 4);
        s += __shfl_xor(s, 8);
        if (tu == 0)
            scores[(size_t)b * Fdim + f0 + tf + 16 * i] = s + vb;
    }
}

__global__ __launch_bounds__(256) void softmax_kernel(float* __restrict__ sc)
{
    __shared__ float red[256];
    const int b = blockIdx.x;
    const int tid = threadIdx.x;
    float* row = sc + (size_t)b * Fdim;

    float v[16];
    float m = -INFINITY;
    #pragma unroll
    for (int i = 0; i < 16; ++i) {
        v[i] = row[tid + 256 * i];
        m = fmaxf(m, v[i]);
    }
    red[tid] = m;
    __syncthreads();
    for (int s = 128; s > 0; s >>= 1) {
        if (tid < s) red[tid] = fmaxf(red[tid], red[tid + s]);
        __syncthreads();
    }
    m = red[0];
    __syncthreads();

    float sum = 0.f;
    #pragma unroll
    for (int i = 0; i < 16; ++i) {
        v[i] = expf(v[i] - m);
        sum += v[i];
    }
    red[tid] = sum;
    __syncthreads();
    for (int s = 128; s > 0; s >>= 1) {
        if (tid < s) red[tid] += red[tid + s];
        __syncthreads();
    }
    const float inv = 1.f / red[0];
    #pragma unroll
    for (int i = 0; i < 16; ++i)
        row[tid + 256 * i] = v[i] * inv;
}

__global__ __launch_bounds__(256) void context_kernel(
    const float* __restrict__ feat, const float* __restrict__ wts,
    float* __restrict__ ctx)
{
    const int b  = blockIdx.y;
    const int fc = blockIdx.x;
    const int e  = threadIdx.x;

    const float* fp = feat + ((size_t)b * Fdim + (size_t)fc * 256) * Edim + e;
    const float* wp = wts + (size_t)b * Fdim + (size_t)fc * 256;

    float acc = 0.f;
    #pragma unroll 8
    for (int f = 0; f < 256; ++f)
        acc = fmaf(wp[f], fp[(size_t)f * Edim], acc);

    atomicAdd(&ctx[(size_t)b * Edim + e], acc);
}

// ---------------------------------------------------------------------------
extern "C" void kernel_launch(void* const* d_in, const int* in_sizes, int n_in,
                              void* d_out, int out_size, void* d_ws, size_t ws_size,
                              hipStream_t stream)
{
    const float* features = (const float*)d_in[0];
    const float* hidden   = (const float*)d_in[1];
    const float* W1w      = (const float*)d_in[2];
    const float* W1b      = (const float*)d_in[3];
    const float* W2w      = (const float*)d_in[4];
    const float* W2b      = (const float*)d_in[5];
    const float* Vw       = (const float*)d_in[6];
    const float* Vb       = (const float*)d_in[7];

    float* ctx = (float*)d_out;                       // (B,E)
    float* wts = (float*)d_out + (size_t)Bdim * Edim; // (B,F)

    // Workspace layout:
    //   cb    128 KiB | W1Ts 256 KiB | scr 1 MiB | pm 8 KiB | ps 8 KiB
    //   pc    2 MiB (64 b x 32 chunks x 256 e)
    float*          cb   = (float*)d_ws;
    unsigned short* W1Ts = (unsigned short*)((char*)d_ws + 131072);
    float*          scr  = (float*)((char*)d_ws + 393216);
    float*          pm   = (float*)((char*)d_ws + 1441792);
    float*          ps   = (float*)((char*)d_ws + 14500 * 1024);   // see below
    float*          pc   = (float*)((char*)d_ws + 1466368 + 8192);
    // recompute cleanly:
    pm = (float*)((char*)d_ws + 1441792);                  // 8 KiB
    ps = (float*)((char*)d_ws + 1441792 + 8192);           // 8 KiB
    pc = (float*)((char*)d_ws + 1441792 + 16384);          // 2 MiB
    const size_t NEED = 1441792 + 16384 + (size_t)Bdim * 32 * Edim * sizeof(float);
    const int mfma_ok = (ws_size >= NEED) ? 1 : 0;

    // prep: proj_h (128) + W1 transpose (32) + ctx zero (16) in one dispatch
    prep_kernel<<<176, 256, 0, stream>>>(hidden, W2w, W1b, W2b, cb,
                                         W1w, W1Ts, ctx, mfma_ok);

    if (mfma_ok) {
        dim3 sgrid(Fdim / 128, Bdim);       // (32, 64)
        score_mfma4_kernel<<<sgrid, 256, 0, stream>>>(features, W1Ts, Vw, Vb, cb,
                                                      scr, pm, ps, pc);
        merge_kernel<<<Bdim, 256, 0, stream>>>(scr, pm, ps, pc, wts, ctx);
    } else {
        dim3 sgrid(Fdim / TFt, Bdim);
        score_kernel<<<sgrid, 256, 0, stream>>>(features, W1w, Vw, Vb, cb, wts);
        softmax_kernel<<<Bdim, 256, 0, stream>>>(wts);
        dim3 cgrid(16, Bdim);
        context_kernel<<<cgrid, 256, 0, stream>>>(features, wts, ctx);
    }
}